// Round 9
// baseline (1175.404 us; speedup 1.0000x reference)
//
#include <hip/hip_runtime.h>

#define Vn 10000
#define En 60000
#define Bb 8
#define LAT 512
#define HID 256
#define NL 5
#define Mrows (Bb * Vn)   // 80000

typedef __attribute__((ext_vector_type(4))) int    i32x4;
typedef __attribute__((ext_vector_type(4))) float  f32x4;
typedef __attribute__((ext_vector_type(8))) short  bf16x8;
typedef __attribute__((ext_vector_type(4))) unsigned short u16x4;

__device__ __forceinline__ float bf2f(unsigned short u) {
    union { unsigned int u; float f; } c;
    c.u = ((unsigned int)u) << 16;
    return c.f;
}
__device__ __forceinline__ unsigned short f2bf(float f) {
    union { float f; unsigned int u; } c;
    c.f = f;
    unsigned int u = c.u + 0x7FFFu + ((c.u >> 16) & 1u);  // RNE
    return (unsigned short)(u >> 16);
}

// ---------------- graph preprocessing (fp32/int) ----------------

__global__ void k_init(int* cnt, int* cur) {
    int i = blockIdx.x * blockDim.x + threadIdx.x;
    if (i < Vn) { cnt[i] = 0; cur[i] = 0; }
}

__global__ void k_count(const int* __restrict__ dst, int* __restrict__ cnt) {
    int e = blockIdx.x * blockDim.x + threadIdx.x;
    if (e < En) atomicAdd(&cnt[dst[e]], 1);
}

__global__ void k_dinv(const int* __restrict__ cnt, float* __restrict__ dinv,
                       float* __restrict__ selfn) {
    int v = blockIdx.x * blockDim.x + threadIdx.x;
    if (v < Vn) {
        float d = (float)cnt[v] + 1.0f;   // +1 self loop
        float r = rsqrtf(d);
        dinv[v] = r;
        selfn[v] = r * r;
    }
}

__global__ void k_scan(const int* __restrict__ cnt, int* __restrict__ rowptr) {
    __shared__ int part[1024];
    const int PER = 10;
    int tid = threadIdx.x;
    int base = tid * PER;
    int local[PER];
    int s = 0;
#pragma unroll
    for (int i = 0; i < PER; ++i) {
        int idx = base + i;
        int c = (idx < Vn) ? cnt[idx] : 0;
        local[i] = s;
        s += c;
    }
    part[tid] = s;
    __syncthreads();
    for (int off = 1; off < 1024; off <<= 1) {
        int add = (tid >= off) ? part[tid - off] : 0;
        __syncthreads();
        part[tid] += add;
        __syncthreads();
    }
    int chunk_base = part[tid] - s;
#pragma unroll
    for (int i = 0; i < PER; ++i) {
        int idx = base + i;
        if (idx < Vn) rowptr[idx] = chunk_base + local[i];
    }
    if (tid == 1023) rowptr[Vn] = part[1023];
}

__global__ void k_fill(const int* __restrict__ src, const int* __restrict__ dst,
                       const float* __restrict__ dinv, const int* __restrict__ rowptr,
                       int* __restrict__ cur, int* __restrict__ csr_src,
                       float* __restrict__ csr_norm) {
    int e = blockIdx.x * blockDim.x + threadIdx.x;
    if (e < En) {
        int s = src[e], d = dst[e];
        int p = atomicAdd(&cur[d], 1);
        int idx = rowptr[d] + p;
        csr_src[idx] = s;
        csr_norm[idx] = dinv[s] * dinv[d];
    }
}

// ---------------- weight convert fp32 -> bf16 ----------------

__global__ void k_wcvt(const float* __restrict__ W, unsigned short* __restrict__ Wb, int n) {
    int i = blockIdx.x * blockDim.x + threadIdx.x;
    if (i < n) Wb[i] = f2bf(W[i]);
}

// ---------------- input layer ----------------

// latc[b][h] = input_b[h] + dot(latent[b,:], input_W[h,3:]); 4-way k-split + quad reduce.
// Also packs w3p[c][h] = input_W[h][c] (c=0..2) for vectorized k_input.
__global__ __launch_bounds__(256) void k_latc(const float* __restrict__ latent,
                                              const float* __restrict__ input_W,
                                              const float* __restrict__ input_b,
                                              float* __restrict__ latc,
                                              float* __restrict__ w3p) {
    int gid = blockIdx.x * 256 + threadIdx.x;   // 32 blocks -> 8192 threads
    int q = gid & 3;
    int i = gid >> 2;                            // 0..2047 = b*256+h
    int b = i >> 8, h = i & 255;
    const float* wr = input_W + (size_t)h * (LAT + 3) + 3 + q * 128;
    const float* lr = latent + (size_t)b * LAT + q * 128;
    float s = 0.0f;
#pragma unroll 8
    for (int k = 0; k < 128; ++k) s = fmaf(lr[k], wr[k], s);
    s += __shfl_xor(s, 1, 64);
    s += __shfl_xor(s, 2, 64);
    if (q == 0) latc[i] = s + input_b[h];
    if (gid < 768) w3p[gid] = input_W[(size_t)(gid & 255) * (LAT + 3) + (gid >> 8)];
}

// X[row][h] = relu(xyz[v]·w3[h] + latc[b][h]); thread = 8 features, 16B store
__global__ __launch_bounds__(256) void k_input(const float* __restrict__ xyz,
                                               const float* __restrict__ w3p,
                                               const float* __restrict__ latc,
                                               unsigned short* __restrict__ X) {
    int gid = blockIdx.x * 256 + threadIdx.x;    // Mrows*32
    int row = gid >> 5;
    int hc = (gid & 31) << 3;
    int b = row / Vn;
    int v = row - b * Vn;
    float x0 = xyz[v * 3 + 0], x1 = xyz[v * 3 + 1], x2 = xyz[v * 3 + 2];
    const float* lc = latc + b * HID + hc;
    u16x4 o0, o1;
#pragma unroll
    for (int j = 0; j < 8; ++j) {
        float s = lc[j];
        s = fmaf(x0, w3p[hc + j], s);
        s = fmaf(x1, w3p[256 + hc + j], s);
        s = fmaf(x2, w3p[512 + hc + j], s);
        unsigned short r = f2bf(fmaxf(s, 0.0f));
        if (j < 4) o0[j] = r; else o1[j - 4] = r;
    }
    u16x4* dst = (u16x4*)&X[(size_t)row * HID + hc];
    dst[0] = o0;
    dst[1] = o1;
}

// ---------------- fused layer: X' = relu((S·X)·W^T + b) ----------------
// Phase 1: each wave aggregates 16 rows (selfn*self + sum norm*neighbor, fp32)
//          and writes bf16 rows straight into the swizzled A-tile LDS.
// Phase 2: MFMA GEMM from LDS (wave = 64Mx64N, W register-resident),
//          bias+relu epilogue, C restaged through LDS (same swizzle), 16B stores.

__global__ __launch_bounds__(256) void k_fused(const unsigned short* __restrict__ Xin,
                                               const unsigned short* __restrict__ Wb,
                                               const float* __restrict__ bias,
                                               const int* __restrict__ rowptr,
                                               const int* __restrict__ csr_src,
                                               const float* __restrict__ csr_norm,
                                               const float* __restrict__ selfn,
                                               unsigned short* __restrict__ Xout) {
    __shared__ __align__(16) char smem[32768];
    const int t = threadIdx.x;
    const int w = t >> 6;
    const int l = t & 63;
    const int m0 = blockIdx.x * 64;
    const int n0w = w * 64;
    const int lr = l & 15;   // B col / C col
    const int lg = l >> 4;   // k-group

    // B fragments: lane l holds W[n0w+nt*16+lr][ks*32 + lg*8 + 0..7]
    bf16x8 Bf[4][8];
#pragma unroll
    for (int nt = 0; nt < 4; ++nt) {
        const unsigned short* wp = Wb + (size_t)(n0w + nt * 16 + lr) * HID + lg * 8;
#pragma unroll
        for (int ks = 0; ks < 8; ++ks)
            Bf[nt][ks] = __builtin_bit_cast(bf16x8, *(const i32x4*)(wp + ks * 32));
    }

    // Phase 1: aggregate 16 rows per wave into LDS (swizzled bf16)
    {
        const int f = l << 2;            // 4 features per lane (8B)
        for (int rr = 0; rr < 16; ++rr) {
            const int r = w * 16 + rr;   // row within tile
            const int row = m0 + r;
            const int b = row / Vn;
            const int v = row - b * Vn;
            const size_t bbase = (size_t)b * Vn * HID;

            u16x4 hs = *(const u16x4*)&Xin[(size_t)row * HID + f];
            float sn = selfn[v];
            float a0 = sn * bf2f(hs[0]), a1 = sn * bf2f(hs[1]);
            float a2 = sn * bf2f(hs[2]), a3 = sn * bf2f(hs[3]);

            int s = rowptr[v], e = rowptr[v + 1];
            int i = s;
            for (; i + 2 <= e; i += 2) {
                float n0 = csr_norm[i], n1 = csr_norm[i + 1];
                int s0 = csr_src[i], s1 = csr_src[i + 1];
                u16x4 h0 = *(const u16x4*)&Xin[bbase + (size_t)s0 * HID + f];
                u16x4 h1 = *(const u16x4*)&Xin[bbase + (size_t)s1 * HID + f];
                a0 = fmaf(n0, bf2f(h0[0]), a0); a1 = fmaf(n0, bf2f(h0[1]), a1);
                a2 = fmaf(n0, bf2f(h0[2]), a2); a3 = fmaf(n0, bf2f(h0[3]), a3);
                a0 = fmaf(n1, bf2f(h1[0]), a0); a1 = fmaf(n1, bf2f(h1[1]), a1);
                a2 = fmaf(n1, bf2f(h1[2]), a2); a3 = fmaf(n1, bf2f(h1[3]), a3);
            }
            if (i < e) {
                float n0 = csr_norm[i];
                u16x4 h0 = *(const u16x4*)&Xin[bbase + (size_t)csr_src[i] * HID + f];
                a0 = fmaf(n0, bf2f(h0[0]), a0); a1 = fmaf(n0, bf2f(h0[1]), a1);
                a2 = fmaf(n0, bf2f(h0[2]), a2); a3 = fmaf(n0, bf2f(h0[3]), a3);
            }
            u16x4 ov;
            ov[0] = f2bf(a0); ov[1] = f2bf(a1); ov[2] = f2bf(a2); ov[3] = f2bf(a3);
            int boff = f * 2;            // byte offset within 512B row
            int addr = r * 512 + (boff ^ ((r & 7) << 4));
            *(u16x4*)(smem + addr) = ov;
        }
    }
    __syncthreads();

    // Phase 2: MFMA GEMM from LDS
    f32x4 acc[4][4];
#pragma unroll
    for (int mt = 0; mt < 4; ++mt)
#pragma unroll
        for (int nt = 0; nt < 4; ++nt)
            acc[mt][nt] = (f32x4){0.f, 0.f, 0.f, 0.f};

#pragma unroll
    for (int ks = 0; ks < 8; ++ks) {
#pragma unroll
        for (int mt = 0; mt < 4; ++mt) {
            int row = mt * 16 + lr;
            int colb = ks * 64 + lg * 16;
            int addr = row * 512 + (colb ^ ((row & 7) << 4));
            bf16x8 a = __builtin_bit_cast(bf16x8, *(const i32x4*)(smem + addr));
#pragma unroll
            for (int nt = 0; nt < 4; ++nt)
                acc[mt][nt] = __builtin_amdgcn_mfma_f32_16x16x32_bf16(
                    a, Bf[nt][ks], acc[mt][nt], 0, 0, 0);
        }
    }

    __syncthreads();  // done reading A-LDS; reuse as C staging

    float bnt[4];
#pragma unroll
    for (int nt = 0; nt < 4; ++nt) bnt[nt] = bias[n0w + nt * 16 + lr];

#pragma unroll
    for (int mt = 0; mt < 4; ++mt)
#pragma unroll
        for (int nt = 0; nt < 4; ++nt)
#pragma unroll
            for (int r = 0; r < 4; ++r) {
                int row = mt * 16 + lg * 4 + r;          // C/D: row=(l>>4)*4+reg
                int col = n0w + nt * 16 + lr;            // C/D: col=l&15
                float vv = fmaxf(acc[mt][nt][r] + bnt[nt], 0.0f);
                int addr = row * 512 + (((col * 2) & 511) ^ ((row & 7) << 4));
                *(unsigned short*)(smem + addr) = f2bf(vv);
            }
    __syncthreads();

    char* dstb = (char*)(Xout + (size_t)m0 * HID);
#pragma unroll
    for (int i = 0; i < 8; ++i) {
        int x = i * 4096 + t * 16;
        int sw = (x & ~511) | ((x & 511) ^ (((x >> 9) & 7) << 4));
        *(i32x4*)(dstb + x) = *(const i32x4*)(smem + sw);
    }
}

// ---------------- output layer ----------------

__global__ __launch_bounds__(256) void k_out(const unsigned short* __restrict__ X,
                                             const float* __restrict__ oW,
                                             const float* __restrict__ ob,
                                             float* __restrict__ disp) {
    int wid = threadIdx.x >> 6;
    int lane = threadIdx.x & 63;
    int bv = blockIdx.x * 4 + wid;
    int f = lane << 2;
    u16x4 xv = *(const u16x4*)&X[(size_t)bv * HID + f];
    float x0 = bf2f(xv[0]), x1 = bf2f(xv[1]), x2 = bf2f(xv[2]), x3 = bf2f(xv[3]);
    float p[3];
#pragma unroll
    for (int c = 0; c < 3; ++c) {
        f32x4 wv = *(const f32x4*)&oW[c * HID + f];
        p[c] = x0 * wv[0] + x1 * wv[1] + x2 * wv[2] + x3 * wv[3];
    }
#pragma unroll
    for (int off = 32; off > 0; off >>= 1) {
#pragma unroll
        for (int c = 0; c < 3; ++c) p[c] += __shfl_down(p[c], off, 64);
    }
    if (lane == 0) {
#pragma unroll
        for (int c = 0; c < 3; ++c) disp[(size_t)bv * 3 + c] = p[c] + ob[c];
    }
}

// ---------------- launch ----------------

extern "C" void kernel_launch(void* const* d_in, const int* in_sizes, int n_in,
                              void* d_out, int out_size, void* d_ws, size_t ws_size,
                              hipStream_t stream) {
    const float* xyz     = (const float*)d_in[0];
    const float* latent  = (const float*)d_in[1];
    const int*   eidx    = (const int*)d_in[2];
    const float* input_W = (const float*)d_in[3];
    const float* input_b = (const float*)d_in[4];
    const float* conv_W  = (const float*)d_in[5];
    const float* conv_b  = (const float*)d_in[6];
    const float* out_W   = (const float*)d_in[7];
    const float* out_b   = (const float*)d_in[8];
    float* disp = (float*)d_out;

    const int* src = eidx;
    const int* dst = eidx + En;

    char* base = (char*)d_ws;
    size_t off = 0;
    auto alloc = [&](size_t bytes) {
        size_t o = off;
        off = (off + bytes + 255) & ~(size_t)255;
        return (void*)(base + o);
    };
    int*   cnt      = (int*)alloc(Vn * 4);
    int*   cur      = (int*)alloc(Vn * 4);
    float* dinv     = (float*)alloc(Vn * 4);
    float* selfn    = (float*)alloc(Vn * 4);
    int*   rowptr   = (int*)alloc((Vn + 1) * 4);
    int*   csr_src  = (int*)alloc(En * 4);
    float* csr_norm = (float*)alloc(En * 4);
    float* latc     = (float*)alloc(Bb * HID * 4);
    float* w3p      = (float*)alloc(3 * HID * 4);
    unsigned short* Wb = (unsigned short*)alloc((size_t)NL * HID * HID * 2);
    unsigned short* X  = (unsigned short*)alloc((size_t)Mrows * HID * 2);
    unsigned short* Xa = (unsigned short*)alloc((size_t)Mrows * HID * 2);

    // graph preprocessing
    k_init<<<(Vn + 255) / 256, 256, 0, stream>>>(cnt, cur);
    k_count<<<(En + 255) / 256, 256, 0, stream>>>(dst, cnt);
    k_dinv<<<(Vn + 255) / 256, 256, 0, stream>>>(cnt, dinv, selfn);
    k_scan<<<1, 1024, 0, stream>>>(cnt, rowptr);
    k_fill<<<(En + 255) / 256, 256, 0, stream>>>(src, dst, dinv, rowptr, cur, csr_src, csr_norm);

    // weights -> bf16
    k_wcvt<<<(NL * HID * HID + 255) / 256, 256, 0, stream>>>(conv_W, Wb, NL * HID * HID);

    // input layer
    k_latc<<<32, 256, 0, stream>>>(latent, input_W, input_b, latc, w3p);
    k_input<<<Mrows * 32 / 256, 256, 0, stream>>>(xyz, w3p, latc, X);

    // conv layers (fused aggregate+GEMM), ping-pong X <-> Xa
    unsigned short* ping = X;
    unsigned short* pong = Xa;
    for (int l = 0; l < NL; ++l) {
        k_fused<<<Mrows / 64, 256, 0, stream>>>(ping, Wb + (size_t)l * HID * HID,
                                                conv_b + (size_t)l * HID,
                                                rowptr, csr_src, csr_norm, selfn, pong);
        unsigned short* tmp = ping; ping = pong; pong = tmp;
    }

    // output layer
    k_out<<<Mrows / 4, 256, 0, stream>>>(ping, out_W, out_b, disp);
}

// Round 10
// 514.133 us; speedup vs baseline: 2.2862x; 2.2862x over previous
//
#include <hip/hip_runtime.h>

#define Vn 10000
#define En 60000
#define Bb 8
#define LAT 512
#define HID 256
#define NL 5
#define Mrows (Bb * Vn)   // 80000

typedef __attribute__((ext_vector_type(4))) int    i32x4;
typedef __attribute__((ext_vector_type(4))) float  f32x4;
typedef __attribute__((ext_vector_type(8))) short  bf16x8;
typedef __attribute__((ext_vector_type(4))) unsigned short u16x4;

__device__ __forceinline__ float bf2f(unsigned short u) {
    union { unsigned int u; float f; } c;
    c.u = ((unsigned int)u) << 16;
    return c.f;
}
__device__ __forceinline__ unsigned short f2bf(float f) {
    union { float f; unsigned int u; } c;
    c.f = f;
    unsigned int u = c.u + 0x7FFFu + ((c.u >> 16) & 1u);  // RNE
    return (unsigned short)(u >> 16);
}

// ---------------- graph preprocessing (fp32/int) ----------------

__global__ void k_init(int* cnt, int* cur) {
    int i = blockIdx.x * blockDim.x + threadIdx.x;
    if (i < Vn) { cnt[i] = 0; cur[i] = 0; }
}

__global__ void k_count(const int* __restrict__ dst, int* __restrict__ cnt) {
    int e = blockIdx.x * blockDim.x + threadIdx.x;
    if (e < En) atomicAdd(&cnt[dst[e]], 1);
}

__global__ void k_dinv(const int* __restrict__ cnt, float* __restrict__ dinv,
                       float* __restrict__ selfn) {
    int v = blockIdx.x * blockDim.x + threadIdx.x;
    if (v < Vn) {
        float d = (float)cnt[v] + 1.0f;   // +1 self loop
        float r = rsqrtf(d);
        dinv[v] = r;
        selfn[v] = r * r;
    }
}

__global__ void k_scan(const int* __restrict__ cnt, int* __restrict__ rowptr) {
    __shared__ int part[1024];
    const int PER = 10;
    int tid = threadIdx.x;
    int base = tid * PER;
    int local[PER];
    int s = 0;
#pragma unroll
    for (int i = 0; i < PER; ++i) {
        int idx = base + i;
        int c = (idx < Vn) ? cnt[idx] : 0;
        local[i] = s;
        s += c;
    }
    part[tid] = s;
    __syncthreads();
    for (int off = 1; off < 1024; off <<= 1) {
        int add = (tid >= off) ? part[tid - off] : 0;
        __syncthreads();
        part[tid] += add;
        __syncthreads();
    }
    int chunk_base = part[tid] - s;
#pragma unroll
    for (int i = 0; i < PER; ++i) {
        int idx = base + i;
        if (idx < Vn) rowptr[idx] = chunk_base + local[i];
    }
    if (tid == 1023) rowptr[Vn] = part[1023];
}

__global__ void k_fill(const int* __restrict__ src, const int* __restrict__ dst,
                       const float* __restrict__ dinv, const int* __restrict__ rowptr,
                       int* __restrict__ cur, int* __restrict__ csr_src,
                       float* __restrict__ csr_norm) {
    int e = blockIdx.x * blockDim.x + threadIdx.x;
    if (e < En) {
        int s = src[e], d = dst[e];
        int p = atomicAdd(&cur[d], 1);
        int idx = rowptr[d] + p;
        csr_src[idx] = s;
        csr_norm[idx] = dinv[s] * dinv[d];
    }
}

// ---------------- weight convert fp32 -> bf16 ----------------

__global__ void k_wcvt(const float* __restrict__ W, unsigned short* __restrict__ Wb, int n) {
    int i = blockIdx.x * blockDim.x + threadIdx.x;
    if (i < n) Wb[i] = f2bf(W[i]);
}

// ---------------- input layer ----------------

__global__ __launch_bounds__(256) void k_latc(const float* __restrict__ latent,
                                              const float* __restrict__ input_W,
                                              const float* __restrict__ input_b,
                                              float* __restrict__ latc,
                                              float* __restrict__ w3p) {
    int gid = blockIdx.x * 256 + threadIdx.x;   // 32 blocks -> 8192 threads
    int q = gid & 3;
    int i = gid >> 2;                            // 0..2047 = b*256+h
    int b = i >> 8, h = i & 255;
    const float* wr = input_W + (size_t)h * (LAT + 3) + 3 + q * 128;
    const float* lr = latent + (size_t)b * LAT + q * 128;
    float s = 0.0f;
#pragma unroll 8
    for (int k = 0; k < 128; ++k) s = fmaf(lr[k], wr[k], s);
    s += __shfl_xor(s, 1, 64);
    s += __shfl_xor(s, 2, 64);
    if (q == 0) latc[i] = s + input_b[h];
    if (gid < 768) w3p[gid] = input_W[(size_t)(gid & 255) * (LAT + 3) + (gid >> 8)];
}

// X[row][h] = relu(xyz[v]·w3[h] + latc[b][h]); thread = 8 features, 16B store
__global__ __launch_bounds__(256) void k_input(const float* __restrict__ xyz,
                                               const float* __restrict__ w3p,
                                               const float* __restrict__ latc,
                                               unsigned short* __restrict__ X) {
    int gid = blockIdx.x * 256 + threadIdx.x;    // Mrows*32
    int row = gid >> 5;
    int hc = (gid & 31) << 3;
    int b = row / Vn;
    int v = row - b * Vn;
    float x0 = xyz[v * 3 + 0], x1 = xyz[v * 3 + 1], x2 = xyz[v * 3 + 2];
    const float* lc = latc + b * HID + hc;
    u16x4 o0, o1;
#pragma unroll
    for (int j = 0; j < 8; ++j) {
        float s = lc[j];
        s = fmaf(x0, w3p[hc + j], s);
        s = fmaf(x1, w3p[256 + hc + j], s);
        s = fmaf(x2, w3p[512 + hc + j], s);
        unsigned short r = f2bf(fmaxf(s, 0.0f));
        if (j < 4) o0[j] = r; else o1[j - 4] = r;
    }
    u16x4* dst = (u16x4*)&X[(size_t)row * HID + hc];
    dst[0] = o0;
    dst[1] = o1;
}

// ---------------- aggregation: Xa[bv] = selfn[v]*X[bv] + sum_e norm*X[b,src] ----
// One wave per row: 12-VGPR, 80000 waves of TLP. Do NOT fuse with the GEMM —
// holding its 128-VGPR B-fragments through this latency-bound gather cost 2.3x (R9).

__global__ __launch_bounds__(256) void k_agg(const unsigned short* __restrict__ Xin,
                                             unsigned short* __restrict__ Xa,
                                             const int* __restrict__ rowptr,
                                             const int* __restrict__ csr_src,
                                             const float* __restrict__ csr_norm,
                                             const float* __restrict__ selfn) {
    int wid = threadIdx.x >> 6;
    int lane = threadIdx.x & 63;
    int bv = blockIdx.x * 4 + wid;
    int b = bv / Vn;
    int v = bv - b * Vn;
    int f = lane << 2;
    size_t bbase = (size_t)b * Vn * HID;

    u16x4 hs = *(const u16x4*)&Xin[(size_t)bv * HID + f];
    float sn = selfn[v];
    float a0 = sn * bf2f(hs[0]), a1 = sn * bf2f(hs[1]);
    float a2 = sn * bf2f(hs[2]), a3 = sn * bf2f(hs[3]);

    int s = rowptr[v], e = rowptr[v + 1];
    int i = s;
    for (; i + 2 <= e; i += 2) {
        float n0 = csr_norm[i], n1 = csr_norm[i + 1];
        int s0 = csr_src[i], s1 = csr_src[i + 1];
        u16x4 h0 = *(const u16x4*)&Xin[bbase + (size_t)s0 * HID + f];
        u16x4 h1 = *(const u16x4*)&Xin[bbase + (size_t)s1 * HID + f];
        a0 = fmaf(n0, bf2f(h0[0]), a0); a1 = fmaf(n0, bf2f(h0[1]), a1);
        a2 = fmaf(n0, bf2f(h0[2]), a2); a3 = fmaf(n0, bf2f(h0[3]), a3);
        a0 = fmaf(n1, bf2f(h1[0]), a0); a1 = fmaf(n1, bf2f(h1[1]), a1);
        a2 = fmaf(n1, bf2f(h1[2]), a2); a3 = fmaf(n1, bf2f(h1[3]), a3);
    }
    if (i < e) {
        float n0 = csr_norm[i];
        u16x4 h0 = *(const u16x4*)&Xin[bbase + (size_t)csr_src[i] * HID + f];
        a0 = fmaf(n0, bf2f(h0[0]), a0); a1 = fmaf(n0, bf2f(h0[1]), a1);
        a2 = fmaf(n0, bf2f(h0[2]), a2); a3 = fmaf(n0, bf2f(h0[3]), a3);
    }
    u16x4 r;
    r[0] = f2bf(a0); r[1] = f2bf(a1); r[2] = f2bf(a2); r[3] = f2bf(a3);
    *(u16x4*)&Xa[(size_t)bv * HID + f] = r;
}

// ---------------- MFMA GEMM: X' = relu(Xa·W^T + b), bf16 in/out, f32 accum ----------------
// Block: 64 M x 256 N, 4 waves; wave = 64Mx64N. W register-resident; A-tile LDS
// XOR-swizzled; C restaged through same LDS with same swizzle (both-sides rule).

__global__ __launch_bounds__(256) void k_gemm(const unsigned short* __restrict__ A,
                                              const unsigned short* __restrict__ Wb,
                                              const float* __restrict__ bias,
                                              unsigned short* __restrict__ Xout) {
    __shared__ __align__(16) char smem[32768];
    const int t = threadIdx.x;
    const int w = t >> 6;
    const int l = t & 63;
    const int m0 = blockIdx.x * 64;
    const int n0w = w * 64;
    const int lr = l & 15;
    const int lg = l >> 4;

    bf16x8 Bf[4][8];
#pragma unroll
    for (int nt = 0; nt < 4; ++nt) {
        const unsigned short* wp = Wb + (size_t)(n0w + nt * 16 + lr) * HID + lg * 8;
#pragma unroll
        for (int ks = 0; ks < 8; ++ks)
            Bf[nt][ks] = __builtin_bit_cast(bf16x8, *(const i32x4*)(wp + ks * 32));
    }

    {
        const char* src = (const char*)(A + (size_t)m0 * HID);
#pragma unroll
        for (int i = 0; i < 8; ++i) {
            int x = i * 4096 + t * 16;
            i32x4 v = *(const i32x4*)(src + x);
            int sw = (x & ~511) | ((x & 511) ^ (((x >> 9) & 7) << 4));
            *(i32x4*)(smem + sw) = v;
        }
    }
    __syncthreads();

    f32x4 acc[4][4];
#pragma unroll
    for (int mt = 0; mt < 4; ++mt)
#pragma unroll
        for (int nt = 0; nt < 4; ++nt)
            acc[mt][nt] = (f32x4){0.f, 0.f, 0.f, 0.f};

#pragma unroll
    for (int ks = 0; ks < 8; ++ks) {
#pragma unroll
        for (int mt = 0; mt < 4; ++mt) {
            int row = mt * 16 + lr;
            int colb = ks * 64 + lg * 16;
            int addr = row * 512 + (colb ^ ((row & 7) << 4));
            bf16x8 a = __builtin_bit_cast(bf16x8, *(const i32x4*)(smem + addr));
#pragma unroll
            for (int nt = 0; nt < 4; ++nt)
                acc[mt][nt] = __builtin_amdgcn_mfma_f32_16x16x32_bf16(
                    a, Bf[nt][ks], acc[mt][nt], 0, 0, 0);
        }
    }

    __syncthreads();

    float bnt[4];
#pragma unroll
    for (int nt = 0; nt < 4; ++nt) bnt[nt] = bias[n0w + nt * 16 + lr];

#pragma unroll
    for (int mt = 0; mt < 4; ++mt)
#pragma unroll
        for (int nt = 0; nt < 4; ++nt)
#pragma unroll
            for (int r = 0; r < 4; ++r) {
                int row = mt * 16 + lg * 4 + r;
                int col = n0w + nt * 16 + lr;
                float vv = fmaxf(acc[mt][nt][r] + bnt[nt], 0.0f);
                int addr = row * 512 + (((col * 2) & 511) ^ ((row & 7) << 4));
                *(unsigned short*)(smem + addr) = f2bf(vv);
            }
    __syncthreads();

    char* dstb = (char*)(Xout + (size_t)m0 * HID);
#pragma unroll
    for (int i = 0; i < 8; ++i) {
        int x = i * 4096 + t * 16;
        int sw = (x & ~511) | ((x & 511) ^ (((x >> 9) & 7) << 4));
        *(i32x4*)(dstb + x) = *(const i32x4*)(smem + sw);
    }
}

// ---------------- output layer ----------------

__global__ __launch_bounds__(256) void k_out(const unsigned short* __restrict__ X,
                                             const float* __restrict__ oW,
                                             const float* __restrict__ ob,
                                             float* __restrict__ disp) {
    int wid = threadIdx.x >> 6;
    int lane = threadIdx.x & 63;
    int bv = blockIdx.x * 4 + wid;
    int f = lane << 2;
    u16x4 xv = *(const u16x4*)&X[(size_t)bv * HID + f];
    float x0 = bf2f(xv[0]), x1 = bf2f(xv[1]), x2 = bf2f(xv[2]), x3 = bf2f(xv[3]);
    float p[3];
#pragma unroll
    for (int c = 0; c < 3; ++c) {
        f32x4 wv = *(const f32x4*)&oW[c * HID + f];
        p[c] = x0 * wv[0] + x1 * wv[1] + x2 * wv[2] + x3 * wv[3];
    }
#pragma unroll
    for (int off = 32; off > 0; off >>= 1) {
#pragma unroll
        for (int c = 0; c < 3; ++c) p[c] += __shfl_down(p[c], off, 64);
    }
    if (lane == 0) {
#pragma unroll
        for (int c = 0; c < 3; ++c) disp[(size_t)bv * 3 + c] = p[c] + ob[c];
    }
}

// ---------------- launch ----------------

extern "C" void kernel_launch(void* const* d_in, const int* in_sizes, int n_in,
                              void* d_out, int out_size, void* d_ws, size_t ws_size,
                              hipStream_t stream) {
    const float* xyz     = (const float*)d_in[0];
    const float* latent  = (const float*)d_in[1];
    const int*   eidx    = (const int*)d_in[2];
    const float* input_W = (const float*)d_in[3];
    const float* input_b = (const float*)d_in[4];
    const float* conv_W  = (const float*)d_in[5];
    const float* conv_b  = (const float*)d_in[6];
    const float* out_W   = (const float*)d_in[7];
    const float* out_b   = (const float*)d_in[8];
    float* disp = (float*)d_out;

    const int* src = eidx;
    const int* dst = eidx + En;

    char* base = (char*)d_ws;
    size_t off = 0;
    auto alloc = [&](size_t bytes) {
        size_t o = off;
        off = (off + bytes + 255) & ~(size_t)255;
        return (void*)(base + o);
    };
    int*   cnt      = (int*)alloc(Vn * 4);
    int*   cur      = (int*)alloc(Vn * 4);
    float* dinv     = (float*)alloc(Vn * 4);
    float* selfn    = (float*)alloc(Vn * 4);
    int*   rowptr   = (int*)alloc((Vn + 1) * 4);
    int*   csr_src  = (int*)alloc(En * 4);
    float* csr_norm = (float*)alloc(En * 4);
    float* latc     = (float*)alloc(Bb * HID * 4);
    float* w3p      = (float*)alloc(3 * HID * 4);
    unsigned short* Wb = (unsigned short*)alloc((size_t)NL * HID * HID * 2);
    unsigned short* X  = (unsigned short*)alloc((size_t)Mrows * HID * 2);
    unsigned short* Xa = (unsigned short*)alloc((size_t)Mrows * HID * 2);

    // graph preprocessing
    k_init<<<(Vn + 255) / 256, 256, 0, stream>>>(cnt, cur);
    k_count<<<(En + 255) / 256, 256, 0, stream>>>(dst, cnt);
    k_dinv<<<(Vn + 255) / 256, 256, 0, stream>>>(cnt, dinv, selfn);
    k_scan<<<1, 1024, 0, stream>>>(cnt, rowptr);
    k_fill<<<(En + 255) / 256, 256, 0, stream>>>(src, dst, dinv, rowptr, cur, csr_src, csr_norm);

    // weights -> bf16
    k_wcvt<<<(NL * HID * HID + 255) / 256, 256, 0, stream>>>(conv_W, Wb, NL * HID * HID);

    // input layer
    k_latc<<<32, 256, 0, stream>>>(latent, input_W, input_b, latc, w3p);
    k_input<<<Mrows * 32 / 256, 256, 0, stream>>>(xyz, w3p, latc, X);

    // conv layers: Xa = S·X  then  X = relu(Xa·W^T + b)
    for (int l = 0; l < NL; ++l) {
        k_agg<<<Mrows / 4, 256, 0, stream>>>(X, Xa, rowptr, csr_src, csr_norm, selfn);
        k_gemm<<<Mrows / 64, 256, 0, stream>>>(Xa, Wb + (size_t)l * HID * HID,
                                               conv_b + (size_t)l * HID, X);
    }

    // output layer
    k_out<<<Mrows / 4, 256, 0, stream>>>(X, out_W, out_b, disp);
}